// Round 8
// baseline (103.140 us; speedup 1.0000x reference)
//
#include <hip/hip_runtime.h>
#include <math.h>

#define BLOCK 64
#define BATCH 16384
#define EPG 16     // elements per block: 8 lane-groups x 2 elements each
#define EP 17      // element-slot stride for per-element LDS arrays (odd: bank skew)
#define NDOF 7
#define ACTION_RANGE 50.0f
#define MAX_VEL 20.0f
#define HSTEP 0.1f

// BLOCK==64 -> exactly one wave per workgroup. DS ops from a single wave are
// processed in order by the LDS pipe, so cross-lane LDS communication needs
// no s_barrier — only a compiler fence to forbid reordering. (Validated:
// R14-R20 all passed the harness with this scheme.)
#define WSYNC() asm volatile("" ::: "memory")
// Bound scheduler lookahead at joint-iteration boundaries. Measured neutral
// vs none (R17 vs R20), kept as balloon insurance now that per-iteration
// state is doubled. Emits no instructions.
#define SCHED_FENCE() __builtin_amdgcn_sched_barrier(0)

__device__ __forceinline__ void mat3_mul(float* C, const float* A, const float* B) {
#pragma unroll
  for (int r = 0; r < 3; r++) {
#pragma unroll
    for (int c = 0; c < 3; c++) {
      C[r*3+c] = A[r*3+0]*B[0*3+c] + A[r*3+1]*B[1*3+c] + A[r*3+2]*B[2*3+c];
    }
  }
}

__device__ __forceinline__ void mat3_vec(float* y, const float* A, const float* x) {
#pragma unroll
  for (int r = 0; r < 3; r++)
    y[r] = A[r*3+0]*x[0] + A[r*3+1]*x[1] + A[r*3+2]*x[2];
}

__device__ __forceinline__ void mat3T_vec(float* y, const float* A, const float* x) {
#pragma unroll
  for (int r = 0; r < 3; r++)
    y[r] = A[0*3+r]*x[0] + A[1*3+r]*x[1] + A[2*3+r]*x[2];
}

__device__ __forceinline__ void cross3(float* y, const float* a, const float* b) {
  y[0] = a[1]*b[2] - a[2]*b[1];
  y[1] = a[2]*b[0] - a[0]*b[2];
  y[2] = a[0]*b[1] - a[1]*b[0];
}

// Rodrigues-direct for UNIT axis w (W^2 = ww^T - I):
//   R = cI + sW + (1-c)ww^T ;  G v with G = sI + (1-c)W + (th-s)ww^T
__device__ __forceinline__ void exp_se3(const float* A6, float th, float* R, float* p) {
  float w0 = A6[0], w1 = A6[1], w2 = A6[2];
  float s = __sinf(th);
  float c = __cosf(th);
  float omc = 1.0f - c, tms = th - s;
  float p00 = w0*w0, p01 = w0*w1, p02 = w0*w2;
  float p11 = w1*w1, p12 = w1*w2, p22 = w2*w2;
  R[0] = c + omc*p00;       R[1] = omc*p01 - s*w2;   R[2] = omc*p02 + s*w1;
  R[3] = omc*p01 + s*w2;    R[4] = c + omc*p11;      R[5] = omc*p12 - s*w0;
  R[6] = omc*p02 - s*w1;    R[7] = omc*p12 + s*w0;   R[8] = c + omc*p22;
  float G0 = s + tms*p00,    G1 = tms*p01 - omc*w2,  G2 = tms*p02 + omc*w1;
  float G3 = tms*p01 + omc*w2, G4 = s + tms*p11,     G5 = tms*p12 - omc*w0;
  float G6 = tms*p02 - omc*w1, G7 = tms*p12 + omc*w0, G8 = s + tms*p22;
  p[0] = G0*A6[3] + G1*A6[4] + G2*A6[5];
  p[1] = G3*A6[3] + G4*A6[4] + G5*A6[5];
  p[2] = G6*A6[3] + G7*A6[4] + G8*A6[5];
}

__device__ __forceinline__ float wrap_pi(float x) {
  const float PI_F   = 3.14159265358979323846f;
  const float TWO_PI = 6.28318530717958647692f;
  float a = x + PI_F;
  float r = a - floorf(a * (1.0f / TWO_PI)) * TWO_PI;
  return r - PI_F;
}

// R21 = R17/R20 structure x2-INTERLEAVED: each 8-lane group processes TWO
// elements (a at slot e, b at slot e+8). Grid halves to 1024 -> 1 wave/SIMD.
// Rationale: kernel is latency/ILP-bound (VALUBusy ~60% at 2 waves/SIMD,
// HBM 0.6%, no spill); TLP is capped by grid, scheduler freedom exhausted
// (R20). Two independent SSA chains per phase (sweeps, Cholesky, FK) fill
// the ~40% idle issue slots; total instruction issue is unchanged.
// Keeps: Bm-free adjoint, scalar EP-stride LDS, WSYNC wave-sync, per-joint
// fences (neutral, balloon insurance), FK shuffle tree, launch_bounds(64,1),
// natural allocation. Spill sentinel: hbm_bytes must stay ~2 MB.
__global__ __launch_bounds__(BLOCK, 1) void arm_rk4_kernel(
    const float* __restrict__ g_state, const float* __restrict__ g_action,
    const float* __restrict__ g_M, const float* __restrict__ g_A,
    const float* __restrict__ g_G, const float* __restrict__ g_grav,
    float* __restrict__ g_out_state, float* __restrict__ g_out_ee)
{
  __shared__ float sMR[8][9];
  __shared__ float sMp[8][3];
  __shared__ float sIR[7][9];
  __shared__ float sIp[7][3];
  __shared__ float sA[7][6];
  __shared__ float sG[7][4];
  __shared__ float sg[3];
  __shared__ float sRB[7*12*EP];   // per joint: R[9], Tp[3], per element slot
  __shared__ float sQh[7*6*EP];    // per joint: Vd (lane-7 history)
  __shared__ float tauL[NDOF*EP];
  __shared__ float qaccL[NDOF*EP];
  __shared__ float MllL[28*EP];

  const int tid  = threadIdx.x;
  const int e    = tid >> 3;      // lane-group 0..7
  const int r    = tid & 7;       // role 0..7
  const int base = tid & 0x38;    // first lane of this group
  const int sa   = e;             // LDS slot, element a
  const int sb   = e + 8;         // LDS slot, element b
  const int ba   = blockIdx.x * EPG + e;       // element a
  const int bb   = blockIdx.x * EPG + 8 + e;   // element b

  if (tid < 8) {
    const float* Mi = g_M + tid*16;
    float a1[3] = {Mi[0], Mi[4], Mi[8]};
    float a2[3] = {Mi[1], Mi[5], Mi[9]};
    float p[3]  = {Mi[3], Mi[7], Mi[11]};
    float n1 = sqrtf(a1[0]*a1[0] + a1[1]*a1[1] + a1[2]*a1[2]);
    float b1[3] = {a1[0]/n1, a1[1]/n1, a1[2]/n1};
    float d = a2[0]*b1[0] + a2[1]*b1[1] + a2[2]*b1[2];
    float a2o[3] = {a2[0]-d*b1[0], a2[1]-d*b1[1], a2[2]-d*b1[2]};
    float n2 = sqrtf(a2o[0]*a2o[0] + a2o[1]*a2o[1] + a2o[2]*a2o[2]);
    float b2[3] = {a2o[0]/n2, a2o[1]/n2, a2o[2]/n2};
    float b3[3];
    cross3(b3, b1, b2);
    float R[9] = {b1[0], b2[0], b3[0],  b1[1], b2[1], b3[1],  b1[2], b2[2], b3[2]};
#pragma unroll
    for (int k = 0; k < 9; k++) sMR[tid][k] = R[k];
    sMp[tid][0] = p[0]; sMp[tid][1] = p[1]; sMp[tid][2] = p[2];
    if (tid < 7) {
#pragma unroll
      for (int rr = 0; rr < 3; rr++)
#pragma unroll
        for (int cc = 0; cc < 3; cc++) sIR[tid][rr*3+cc] = R[cc*3+rr];
#pragma unroll
      for (int rr = 0; rr < 3; rr++)
        sIp[tid][rr] = -(R[0*3+rr]*p[0] + R[1*3+rr]*p[1] + R[2*3+rr]*p[2]);
      const float* Ar = g_A + tid*6;
      float nw = sqrtf(Ar[0]*Ar[0] + Ar[1]*Ar[1] + Ar[2]*Ar[2]);
      sA[tid][0] = Ar[0]/nw; sA[tid][1] = Ar[1]/nw; sA[tid][2] = Ar[2]/nw;
      sA[tid][3] = Ar[3];    sA[tid][4] = Ar[4];    sA[tid][5] = Ar[5];
      sG[tid][0] = fabsf(g_G[tid*4+0]);
      sG[tid][1] = fabsf(g_G[tid*4+1]);
      sG[tid][2] = fabsf(g_G[tid*4+2]);
      sG[tid][3] = fabsf(g_G[tid*4+3]);
    }
  }
  if (tid == 0) { sg[0] = g_grav[0]; sg[1] = g_grav[1]; sg[2] = g_grav[2]; }

  float q0a = 0.f, dq0a = 0.f, qsa = 0.f, dqsa = 0.f;
  float q0b = 0.f, dq0b = 0.f, qsb = 0.f, dqsb = 0.f;
  float accqa = 0.f, accda = 0.f, accqb = 0.f, accdb = 0.f;
  if (r < NDOF) {
    q0a  = g_state[ba*14 + r];
    dq0a = g_state[ba*14 + 7 + r];
    q0b  = g_state[bb*14 + r];
    dq0b = g_state[bb*14 + 7 + r];
    float taua = g_action[ba*7 + r] * ACTION_RANGE;
    float taub = g_action[bb*7 + r] * ACTION_RANGE;
    qsa = q0a; dqsa = dq0a;
    qsb = q0b; dqsb = dq0b;
    tauL[r*EP + sa] = taua;
    tauL[r*EP + sb] = taub;
  }
  WSYNC();

#pragma unroll 1
  for (int st = 0; st < 4; st++) {
    float bias_a[NDOF], bias_b[NDOF];   // valid on lane r==7

    // ---- (A) adjoints of joint r for both elements, lanes r<7 ----
    if (r < NDOF) {
      float Ai[6];
#pragma unroll
      for (int k = 0; k < 6; k++) Ai[k] = sA[r][k];
      float IRl[9];
#pragma unroll
      for (int k = 0; k < 9; k++) IRl[k] = sIR[r][k];
      float Ipl[3] = {sIp[r][0], sIp[r][1], sIp[r][2]};
      // element a
      float Rea[9], pea[3];
      exp_se3(Ai, -qsa, Rea, pea);
      float Ta[9];
      mat3_mul(Ta, Rea, IRl);
      float Tpa[3];
      mat3_vec(Tpa, Rea, Ipl);
      Tpa[0] += pea[0]; Tpa[1] += pea[1]; Tpa[2] += pea[2];
      // element b
      float Reb[9], peb[3];
      exp_se3(Ai, -qsb, Reb, peb);
      float Tb[9];
      mat3_mul(Tb, Reb, IRl);
      float Tpb[3];
      mat3_vec(Tpb, Reb, Ipl);
      Tpb[0] += peb[0]; Tpb[1] += peb[1]; Tpb[2] += peb[2];
#pragma unroll
      for (int k = 0; k < 9; k++) {
        sRB[(r*12 + k)*EP + sa] = Ta[k];
        sRB[(r*12 + k)*EP + sb] = Tb[k];
      }
#pragma unroll
      for (int k = 0; k < 3; k++) {
        sRB[(r*12 + 9 + k)*EP + sa] = Tpa[k];
        sRB[(r*12 + 9 + k)*EP + sb] = Tpb[k];
      }
    }
    WSYNC();
    SCHED_FENCE();

    // ---- (BC) fused forward+backward sweep, ALL 8 lanes, 2 elements ----
    {
      float PhwA[NDOF][3], PhvA[NDOF][3], PhwB[NDOF][3], PhvB[NDOF][3];
      float PwA[3] = {0.f,0.f,0.f}, PvA[3] = {0.f,0.f,0.f};
      float QwA[3] = {0.f,0.f,0.f}, QvA[3] = {0.f,0.f,0.f};
      float PwB[3] = {0.f,0.f,0.f}, PvB[3] = {0.f,0.f,0.f};
      float QwB[3] = {0.f,0.f,0.f}, QvB[3] = {0.f,0.f,0.f};
      if (r == 7) {
        QvA[0] = -sg[0]; QvA[1] = -sg[1]; QvA[2] = -sg[2];
        QvB[0] = -sg[0]; QvB[1] = -sg[1]; QvB[2] = -sg[2];
      }
#pragma unroll
      for (int i = 0; i < NDOF; i++) {
        float RmA[9], TplA[3], RmB[9], TplB[3];
#pragma unroll
        for (int k = 0; k < 9; k++) {
          RmA[k] = sRB[(i*12 + k)*EP + sa];
          RmB[k] = sRB[(i*12 + k)*EP + sb];
        }
#pragma unroll
        for (int k = 0; k < 3; k++) {
          TplA[k] = sRB[(i*12 + 9 + k)*EP + sa];
          TplB[k] = sRB[(i*12 + 9 + k)*EP + sb];
        }
        float dqiA = __shfl(dqsa, base + i, 64);
        float dqiB = __shfl(dqsb, base + i, 64);
        float Aw[3] = {sA[i][0], sA[i][1], sA[i][2]};
        float Av[3] = {sA[i][3], sA[i][4], sA[i][5]};
        float cR = (r == i) ? 1.f : 0.f;
        const bool l7 = (r == 7);
        // ---- element a ----
        {
          float Tw[3], t2[3], Tv[3];
          mat3_vec(Tw, RmA, PwA);
          mat3_vec(t2, RmA, PvA);
          cross3(Tv, TplA, Tw);
          float cA = l7 ? dqiA : cR;
#pragma unroll
          for (int k = 0; k < 3; k++) {
            PwA[k] = Tw[k] + cA*Aw[k];
            PvA[k] = Tv[k] + t2[k] + cA*Av[k];
          }
          float Uw[3], u2[3], Uv[3];
          mat3_vec(Uw, RmA, QwA);
          mat3_vec(u2, RmA, QvA);
          cross3(Uv, TplA, Uw);
          float c1[3], c2[3], c3[3];
          cross3(c1, PwA, Aw);
          cross3(c2, PvA, Aw);
          cross3(c3, PwA, Av);
          float c8 = l7 ? dqiA : 0.f;
#pragma unroll
          for (int k = 0; k < 3; k++) {
            QwA[k] = Uw[k] + c8*c1[k];
            QvA[k] = Uv[k] + u2[k] + c8*(c2[k]+c3[k]);
          }
#pragma unroll
          for (int k = 0; k < 3; k++) { PhwA[i][k] = PwA[k]; PhvA[i][k] = PvA[k]; }
        }
        // ---- element b ----
        {
          float Tw[3], t2[3], Tv[3];
          mat3_vec(Tw, RmB, PwB);
          mat3_vec(t2, RmB, PvB);
          cross3(Tv, TplB, Tw);
          float cA = l7 ? dqiB : cR;
#pragma unroll
          for (int k = 0; k < 3; k++) {
            PwB[k] = Tw[k] + cA*Aw[k];
            PvB[k] = Tv[k] + t2[k] + cA*Av[k];
          }
          float Uw[3], u2[3], Uv[3];
          mat3_vec(Uw, RmB, QwB);
          mat3_vec(u2, RmB, QvB);
          cross3(Uv, TplB, Uw);
          float c1[3], c2[3], c3[3];
          cross3(c1, PwB, Aw);
          cross3(c2, PvB, Aw);
          cross3(c3, PwB, Av);
          float c8 = l7 ? dqiB : 0.f;
#pragma unroll
          for (int k = 0; k < 3; k++) {
            QwB[k] = Uw[k] + c8*c1[k];
            QvB[k] = Uv[k] + u2[k] + c8*(c2[k]+c3[k]);
          }
#pragma unroll
          for (int k = 0; k < 3; k++) { PhwB[i][k] = PwB[k]; PhvB[i][k] = PvB[k]; }
        }
        if (r == 7) {
#pragma unroll
          for (int k = 0; k < 3; k++) {
            sQh[(i*6 +     k)*EP + sa] = QwA[k];
            sQh[(i*6 + 3 + k)*EP + sa] = QvA[k];
            sQh[(i*6 +     k)*EP + sb] = QwB[k];
            sQh[(i*6 + 3 + k)*EP + sb] = QvB[k];
          }
        }
        SCHED_FENCE();
      }
      // backward: F' = AdT^T F via R^T(Fw + Fv x Tp), both elements
      float FwA[3] = {0.f,0.f,0.f}, FvA[3] = {0.f,0.f,0.f};
      float FwB[3] = {0.f,0.f,0.f}, FvB[3] = {0.f,0.f,0.f};
#pragma unroll
      for (int i = NDOF-1; i >= 0; i--) {
        if (i < NDOF-1) {
          const int jn = i + 1;
          float RmA[9], TplA[3], RmB[9], TplB[3];
#pragma unroll
          for (int k = 0; k < 9; k++) {
            RmA[k] = sRB[(jn*12 + k)*EP + sa];
            RmB[k] = sRB[(jn*12 + k)*EP + sb];
          }
#pragma unroll
          for (int k = 0; k < 3; k++) {
            TplA[k] = sRB[(jn*12 + 9 + k)*EP + sa];
            TplB[k] = sRB[(jn*12 + 9 + k)*EP + sb];
          }
          {
            float cFT[3];
            cross3(cFT, FvA, TplA);
            float s0[3] = {FwA[0]+cFT[0], FwA[1]+cFT[1], FwA[2]+cFT[2]};
            float nw[3], nv[3];
            mat3T_vec(nw, RmA, s0);
            mat3T_vec(nv, RmA, FvA);
            FwA[0] = nw[0]; FwA[1] = nw[1]; FwA[2] = nw[2];
            FvA[0] = nv[0]; FvA[1] = nv[1]; FvA[2] = nv[2];
          }
          {
            float cFT[3];
            cross3(cFT, FvB, TplB);
            float s0[3] = {FwB[0]+cFT[0], FwB[1]+cFT[1], FwB[2]+cFT[2]};
            float nw[3], nv[3];
            mat3T_vec(nw, RmB, s0);
            mat3T_vec(nv, RmB, FvB);
            FwB[0] = nw[0]; FwB[1] = nw[1]; FwB[2] = nw[2];
            FvB[0] = nv[0]; FvB[1] = nv[1]; FvB[2] = nv[2];
          }
        }
        float gx = sG[i][0], gy = sG[i][1], gz = sG[i][2], m_ = sG[i][3];
        const bool l7 = (r == 7);
        // element a
        {
          float aw[3] = {gx*PhwA[i][0], gy*PhwA[i][1], gz*PhwA[i][2]};
          float av[3] = {m_*PhvA[i][0], m_*PhvA[i][1], m_*PhvA[i][2]};
          float Dw[3], Dv[3];
#pragma unroll
          for (int k = 0; k < 3; k++) {
            Dw[k] = sQh[(i*6 +     k)*EP + sa];
            Dv[k] = sQh[(i*6 + 3 + k)*EP + sa];
          }
          float GDw[3] = {gx*Dw[0], gy*Dw[1], gz*Dw[2]};
          float GDv[3] = {m_*Dv[0], m_*Dv[1], m_*Dv[2]};
          float x1[3], x2[3], x3[3];
          cross3(x1, PhwA[i], aw);
          cross3(x2, PhvA[i], av);
          cross3(x3, PhwA[i], av);
#pragma unroll
          for (int k = 0; k < 3; k++) {
            FwA[k] += l7 ? (GDw[k] + x1[k] + x2[k]) : aw[k];
            FvA[k] += l7 ? (GDv[k] + x3[k])         : av[k];
          }
          float val = FwA[0]*sA[i][0] + FwA[1]*sA[i][1] + FwA[2]*sA[i][2]
                    + FvA[0]*sA[i][3] + FvA[1]*sA[i][4] + FvA[2]*sA[i][5];
          if (r < NDOF && i >= r) MllL[(i*(i+1)/2 + r)*EP + sa] = val;
          if (l7) bias_a[i] = val;
        }
        // element b
        {
          float aw[3] = {gx*PhwB[i][0], gy*PhwB[i][1], gz*PhwB[i][2]};
          float av[3] = {m_*PhvB[i][0], m_*PhvB[i][1], m_*PhvB[i][2]};
          float Dw[3], Dv[3];
#pragma unroll
          for (int k = 0; k < 3; k++) {
            Dw[k] = sQh[(i*6 +     k)*EP + sb];
            Dv[k] = sQh[(i*6 + 3 + k)*EP + sb];
          }
          float GDw[3] = {gx*Dw[0], gy*Dw[1], gz*Dw[2]};
          float GDv[3] = {m_*Dv[0], m_*Dv[1], m_*Dv[2]};
          float x1[3], x2[3], x3[3];
          cross3(x1, PhwB[i], aw);
          cross3(x2, PhvB[i], av);
          cross3(x3, PhwB[i], av);
#pragma unroll
          for (int k = 0; k < 3; k++) {
            FwB[k] += l7 ? (GDw[k] + x1[k] + x2[k]) : aw[k];
            FvB[k] += l7 ? (GDv[k] + x3[k])         : av[k];
          }
          float val = FwB[0]*sA[i][0] + FwB[1]*sA[i][1] + FwB[2]*sA[i][2]
                    + FvB[0]*sA[i][3] + FvB[1]*sA[i][4] + FvB[2]*sA[i][5];
          if (r < NDOF && i >= r) MllL[(i*(i+1)/2 + r)*EP + sb] = val;
          if (l7) bias_b[i] = val;
        }
        SCHED_FENCE();
      }
    }
    WSYNC();

    // ---- (D) two independent Cholesky solves, lane r==7 ----
    if (r == 7) {
      float LmA[28], LmB[28], invdA[NDOF], invdB[NDOF];
#pragma unroll
      for (int idx = 0; idx < 28; idx++) {
        LmA[idx] = MllL[idx*EP + sa];
        LmB[idx] = MllL[idx*EP + sb];
      }
      float yA[NDOF], yB[NDOF];
#pragma unroll
      for (int i = 0; i < NDOF; i++) {
        yA[i] = tauL[i*EP + sa] - bias_a[i];
        yB[i] = tauL[i*EP + sb] - bias_b[i];
      }
#pragma unroll
      for (int k = 0; k < NDOF; k++) {
        float dA = LmA[k*(k+1)/2 + k];
        float dB = LmB[k*(k+1)/2 + k];
#pragma unroll
        for (int m2 = 0; m2 < k; m2++) {
          float lA = LmA[k*(k+1)/2 + m2]; dA -= lA*lA;
          float lB = LmB[k*(k+1)/2 + m2]; dB -= lB*lB;
        }
        dA = sqrtf(dA); dB = sqrtf(dB);
        LmA[k*(k+1)/2 + k] = dA;
        LmB[k*(k+1)/2 + k] = dB;
        float invA = 1.0f / dA, invB = 1.0f / dB;
        invdA[k] = invA; invdB[k] = invB;
#pragma unroll
        for (int i = k+1; i < NDOF; i++) {
          float sA_ = LmA[i*(i+1)/2 + k];
          float sB_ = LmB[i*(i+1)/2 + k];
#pragma unroll
          for (int m2 = 0; m2 < k; m2++) {
            sA_ -= LmA[i*(i+1)/2 + m2]*LmA[k*(k+1)/2 + m2];
            sB_ -= LmB[i*(i+1)/2 + m2]*LmB[k*(k+1)/2 + m2];
          }
          LmA[i*(i+1)/2 + k] = sA_ * invA;
          LmB[i*(i+1)/2 + k] = sB_ * invB;
        }
      }
#pragma unroll
      for (int i = 0; i < NDOF; i++) {
        float sA_ = yA[i], sB_ = yB[i];
#pragma unroll
        for (int m2 = 0; m2 < i; m2++) {
          sA_ -= LmA[i*(i+1)/2 + m2]*yA[m2];
          sB_ -= LmB[i*(i+1)/2 + m2]*yB[m2];
        }
        yA[i] = sA_ * invdA[i];
        yB[i] = sB_ * invdB[i];
      }
      float qacA[NDOF], qacB[NDOF];
#pragma unroll
      for (int i = NDOF-1; i >= 0; i--) {
        float sA_ = yA[i], sB_ = yB[i];
#pragma unroll
        for (int m2 = i+1; m2 < NDOF; m2++) {
          sA_ -= LmA[m2*(m2+1)/2 + i]*qacA[m2];
          sB_ -= LmB[m2*(m2+1)/2 + i]*qacB[m2];
        }
        qacA[i] = sA_ * invdA[i];
        qacB[i] = sB_ * invdB[i];
      }
#pragma unroll
      for (int i = 0; i < NDOF; i++) {
        qaccL[i*EP + sa] = qacA[i];
        qaccL[i*EP + sb] = qacB[i];
      }
    }
    WSYNC();

    // ---- (E) RK4 stage update, lanes r<7, both elements ----
    if (r < NDOF) {
      float aA = qaccL[r*EP + sa];
      float aB = qaccL[r*EP + sb];
      float w = (st == 0 || st == 3) ? 1.0f : 2.0f;
      accqa += w * dqsa;  accda += w * aA;
      accqb += w * dqsb;  accdb += w * aB;
      if (st < 3) {
        float c = (st == 2) ? HSTEP : 0.5f*HSTEP;
        qsa  = q0a  + c * dqsa;  dqsa = dq0a + c * aA;
        qsb  = q0b  + c * dqsb;  dqsb = dq0b + c * aB;
      }
    }
  }

  const float h6 = HSTEP / 6.0f;
  float qfa = 0.f, qfb = 0.f;
  if (r < NDOF) {
    qfa = wrap_pi(q0a + h6*accqa);
    qfb = wrap_pi(q0b + h6*accqb);
    float va  = dq0a + h6*accda;
    float vb  = dq0b + h6*accdb;
    float dqfa = fminf(fmaxf(va, -MAX_VEL), MAX_VEL);
    float dqfb = fminf(fmaxf(vb, -MAX_VEL), MAX_VEL);
    g_out_state[ba*14 + r]     = qfa;
    g_out_state[ba*14 + 7 + r] = dqfa;
    g_out_state[bb*14 + r]     = qfb;
    g_out_state[bb*14 + 7 + r] = dqfb;
  }

  // ---- FK: per-lane leaf + 3-step shuffle tree, both elements ----
  // lane r<7: T_r = M_r * exp(A_r, qf_r); lane 7: T_7 = M_7.
  // Leftward product: lane 0 ends with (M_0 E_0)...(M_6 E_6) M_7; its p is EE.
  float MR[9], Mpl[3];
#pragma unroll
  for (int k = 0; k < 9; k++) MR[k] = sMR[r][k];
  Mpl[0] = sMp[r][0]; Mpl[1] = sMp[r][1]; Mpl[2] = sMp[r][2];
  float SRa[9], Spa[3], SRb[9], Spb[3];
  if (r < NDOF) {
    float Ai[6];
#pragma unroll
    for (int k = 0; k < 6; k++) Ai[k] = sA[r][k];
    float Rea[9], pea[3];
    exp_se3(Ai, qfa, Rea, pea);
    mat3_mul(SRa, MR, Rea);
    float ta[3];
    mat3_vec(ta, MR, pea);
    Spa[0] = ta[0] + Mpl[0]; Spa[1] = ta[1] + Mpl[1]; Spa[2] = ta[2] + Mpl[2];
    float Reb[9], peb[3];
    exp_se3(Ai, qfb, Reb, peb);
    mat3_mul(SRb, MR, Reb);
    float tb[3];
    mat3_vec(tb, MR, peb);
    Spb[0] = tb[0] + Mpl[0]; Spb[1] = tb[1] + Mpl[1]; Spb[2] = tb[2] + Mpl[2];
  } else {
#pragma unroll
    for (int k = 0; k < 9; k++) { SRa[k] = MR[k]; SRb[k] = MR[k]; }
    Spa[0] = Mpl[0]; Spa[1] = Mpl[1]; Spa[2] = Mpl[2];
    Spb[0] = Mpl[0]; Spb[1] = Mpl[1]; Spb[2] = Mpl[2];
  }
#pragma unroll
  for (int off = 1; off < 8; off <<= 1) {
    const int partner = base + ((r + off) & 7);
    float PRa[9], Ppa[3], PRb[9], Ppb[3];
#pragma unroll
    for (int k = 0; k < 9; k++) {
      PRa[k] = __shfl(SRa[k], partner, 64);
      PRb[k] = __shfl(SRb[k], partner, 64);
    }
#pragma unroll
    for (int k = 0; k < 3; k++) {
      Ppa[k] = __shfl(Spa[k], partner, 64);
      Ppb[k] = __shfl(Spb[k], partner, 64);
    }
    float NRa[9], Npa[3], NRb[9], Npb[3];
    mat3_mul(NRa, SRa, PRa);
    mat3_vec(Npa, SRa, Ppa);
    mat3_mul(NRb, SRb, PRb);
    mat3_vec(Npb, SRb, Ppb);
#pragma unroll
    for (int k = 0; k < 9; k++) { SRa[k] = NRa[k]; SRb[k] = NRb[k]; }
    Spa[0] += 0.f; // keep SSA clean
    Spa[0] = Npa[0] + Spa[0]; Spa[1] = Npa[1] + Spa[1]; Spa[2] = Npa[2] + Spa[2];
    Spb[0] = Npb[0] + Spb[0]; Spb[1] = Npb[1] + Spb[1]; Spb[2] = Npb[2] + Spb[2];
  }
  if (r == 0) {
    g_out_ee[ba*2 + 0] = Spa[0];
    g_out_ee[ba*2 + 1] = Spa[1];
    g_out_ee[bb*2 + 0] = Spb[0];
    g_out_ee[bb*2 + 1] = Spb[1];
  }
}

extern "C" void kernel_launch(void* const* d_in, const int* in_sizes, int n_in,
                              void* d_out, int out_size, void* d_ws, size_t ws_size,
                              hipStream_t stream) {
  const float* state  = (const float*)d_in[0];  // (16384,14)
  const float* action = (const float*)d_in[1];  // (16384,7)
  const float* M      = (const float*)d_in[2];  // (8,4,4)
  const float* A      = (const float*)d_in[3];  // (7,6)
  const float* G      = (const float*)d_in[4];  // (7,4)
  const float* grav   = (const float*)d_in[5];  // (3,)
  float* out_state = (float*)d_out;                       // (16384,14)
  float* out_ee    = (float*)d_out + (size_t)BATCH * 14;  // (16384,2)

  arm_rk4_kernel<<<BATCH / EPG, BLOCK, 0, stream>>>(
      state, action, M, A, G, grav, out_state, out_ee);
}

// Round 9
// 90.501 us; speedup vs baseline: 1.1397x; 1.1397x over previous
//
#include <hip/hip_runtime.h>
#include <math.h>

#define BLOCK 64
#define BATCH 16384
#define EPB 8      // elements per block: 8 lanes per element
#define EP 9       // element-dim stride for per-element LDS arrays
#define NDOF 7
#define ACTION_RANGE 50.0f
#define MAX_VEL 20.0f
#define HSTEP 0.1f

// BLOCK==64 -> exactly one wave per workgroup. DS ops from a single wave are
// processed in order by the LDS pipe, so cross-lane LDS communication needs
// no s_barrier — only a compiler fence to forbid reordering. (Validated:
// R14-R21 all passed the harness with this scheme.)
#define WSYNC() asm volatile("" ::: "memory")
// Bound scheduler lookahead at joint-iteration boundaries (measured neutral
// vs none, R17 vs R20; kept because R17 is the best-measured exact config).
#define SCHED_FENCE() __builtin_amdgcn_sched_barrier(0)

__device__ __forceinline__ void mat3_mul(float* C, const float* A, const float* B) {
#pragma unroll
  for (int r = 0; r < 3; r++) {
#pragma unroll
    for (int c = 0; c < 3; c++) {
      C[r*3+c] = A[r*3+0]*B[0*3+c] + A[r*3+1]*B[1*3+c] + A[r*3+2]*B[2*3+c];
    }
  }
}

__device__ __forceinline__ void mat3_vec(float* y, const float* A, const float* x) {
#pragma unroll
  for (int r = 0; r < 3; r++)
    y[r] = A[r*3+0]*x[0] + A[r*3+1]*x[1] + A[r*3+2]*x[2];
}

__device__ __forceinline__ void mat3T_vec(float* y, const float* A, const float* x) {
#pragma unroll
  for (int r = 0; r < 3; r++)
    y[r] = A[0*3+r]*x[0] + A[1*3+r]*x[1] + A[2*3+r]*x[2];
}

__device__ __forceinline__ void cross3(float* y, const float* a, const float* b) {
  y[0] = a[1]*b[2] - a[2]*b[1];
  y[1] = a[2]*b[0] - a[0]*b[2];
  y[2] = a[0]*b[1] - a[1]*b[0];
}

// Rodrigues-direct for UNIT axis w (W^2 = ww^T - I):
//   R = cI + sW + (1-c)ww^T ;  G v with G = sI + (1-c)W + (th-s)ww^T
__device__ __forceinline__ void exp_se3(const float* A6, float th, float* R, float* p) {
  float w0 = A6[0], w1 = A6[1], w2 = A6[2];
  float s = __sinf(th);
  float c = __cosf(th);
  float omc = 1.0f - c, tms = th - s;
  float p00 = w0*w0, p01 = w0*w1, p02 = w0*w2;
  float p11 = w1*w1, p12 = w1*w2, p22 = w2*w2;
  R[0] = c + omc*p00;       R[1] = omc*p01 - s*w2;   R[2] = omc*p02 + s*w1;
  R[3] = omc*p01 + s*w2;    R[4] = c + omc*p11;      R[5] = omc*p12 - s*w0;
  R[6] = omc*p02 - s*w1;    R[7] = omc*p12 + s*w0;   R[8] = c + omc*p22;
  float G0 = s + tms*p00,    G1 = tms*p01 - omc*w2,  G2 = tms*p02 + omc*w1;
  float G3 = tms*p01 + omc*w2, G4 = s + tms*p11,     G5 = tms*p12 - omc*w0;
  float G6 = tms*p02 - omc*w1, G7 = tms*p12 + omc*w0, G8 = s + tms*p22;
  p[0] = G0*A6[3] + G1*A6[4] + G2*A6[5];
  p[1] = G3*A6[3] + G4*A6[4] + G5*A6[5];
  p[2] = G6*A6[3] + G7*A6[4] + G8*A6[5];
}

__device__ __forceinline__ float wrap_pi(float x) {
  const float PI_F   = 3.14159265358979323846f;
  const float TWO_PI = 6.28318530717958647692f;
  float a = x + PI_F;
  float r = a - floorf(a * (1.0f / TWO_PI)) * TWO_PI;
  return r - PI_F;
}

// R22 = R17 verbatim (best-measured: harness 91.57us, kernel ~33us; scalar
// EP-stride LDS, natural ~112 VGPR, Bm-free adjoint, WSYNC wave-sync,
// per-joint fences, FK shuffle tree) + ONE change: lane-7 solve switched
// from Cholesky to LDL^T. Removes all 7 v_sqrt_f32 from the serial critical
// chain (sqrt->rcp->scale->next-diag was strictly chained, ~16cyc each);
// the chain is now FMA + one rcp per step. Same FLOP count, same layout.
// Closed axes (measured): TLP capped at 2 waves/SIMD by grid (R21: halving
// waves for x2-ILP lost — allocator held 112 VGPR and serialized chains);
// float4 LDS (R18), hand-pipelining (R19), occupancy attrs (R15/R16) all
// regressed. Spill sentinel: hbm_bytes must stay ~2 MB.
__global__ __launch_bounds__(BLOCK, 1) void arm_rk4_kernel(
    const float* __restrict__ g_state, const float* __restrict__ g_action,
    const float* __restrict__ g_M, const float* __restrict__ g_A,
    const float* __restrict__ g_G, const float* __restrict__ g_grav,
    float* __restrict__ g_out_state, float* __restrict__ g_out_ee)
{
  __shared__ float sMR[8][9];
  __shared__ float sMp[8][3];
  __shared__ float sIR[7][9];
  __shared__ float sIp[7][3];
  __shared__ float sA[7][6];
  __shared__ float sG[7][4];
  __shared__ float sg[3];
  __shared__ float sRB[7*12*EP];   // per joint: R[9], Tp[3]
  __shared__ float sQh[7*6*EP];    // per joint: Vd (lane-7 history)
  __shared__ float tauL[NDOF*EP];
  __shared__ float qaccL[NDOF*EP];
  __shared__ float MllL[28*EP];

  const int tid  = threadIdx.x;
  const int e    = tid >> 3;      // element slot 0..7
  const int r    = tid & 7;       // role 0..7
  const int base = tid & 0x38;    // first lane of this element group
  const int b    = blockIdx.x * EPB + e;

  if (tid < 8) {
    const float* Mi = g_M + tid*16;
    float a1[3] = {Mi[0], Mi[4], Mi[8]};
    float a2[3] = {Mi[1], Mi[5], Mi[9]};
    float p[3]  = {Mi[3], Mi[7], Mi[11]};
    float n1 = sqrtf(a1[0]*a1[0] + a1[1]*a1[1] + a1[2]*a1[2]);
    float b1[3] = {a1[0]/n1, a1[1]/n1, a1[2]/n1};
    float d = a2[0]*b1[0] + a2[1]*b1[1] + a2[2]*b1[2];
    float a2o[3] = {a2[0]-d*b1[0], a2[1]-d*b1[1], a2[2]-d*b1[2]};
    float n2 = sqrtf(a2o[0]*a2o[0] + a2o[1]*a2o[1] + a2o[2]*a2o[2]);
    float b2[3] = {a2o[0]/n2, a2o[1]/n2, a2o[2]/n2};
    float b3[3];
    cross3(b3, b1, b2);
    float R[9] = {b1[0], b2[0], b3[0],  b1[1], b2[1], b3[1],  b1[2], b2[2], b3[2]};
#pragma unroll
    for (int k = 0; k < 9; k++) sMR[tid][k] = R[k];
    sMp[tid][0] = p[0]; sMp[tid][1] = p[1]; sMp[tid][2] = p[2];
    if (tid < 7) {
#pragma unroll
      for (int rr = 0; rr < 3; rr++)
#pragma unroll
        for (int cc = 0; cc < 3; cc++) sIR[tid][rr*3+cc] = R[cc*3+rr];
#pragma unroll
      for (int rr = 0; rr < 3; rr++)
        sIp[tid][rr] = -(R[0*3+rr]*p[0] + R[1*3+rr]*p[1] + R[2*3+rr]*p[2]);
      const float* Ar = g_A + tid*6;
      float nw = sqrtf(Ar[0]*Ar[0] + Ar[1]*Ar[1] + Ar[2]*Ar[2]);
      sA[tid][0] = Ar[0]/nw; sA[tid][1] = Ar[1]/nw; sA[tid][2] = Ar[2]/nw;
      sA[tid][3] = Ar[3];    sA[tid][4] = Ar[4];    sA[tid][5] = Ar[5];
      sG[tid][0] = fabsf(g_G[tid*4+0]);
      sG[tid][1] = fabsf(g_G[tid*4+1]);
      sG[tid][2] = fabsf(g_G[tid*4+2]);
      sG[tid][3] = fabsf(g_G[tid*4+3]);
    }
  }
  if (tid == 0) { sg[0] = g_grav[0]; sg[1] = g_grav[1]; sg[2] = g_grav[2]; }

  float q0 = 0.f, dq0 = 0.f, qs = 0.f, dqs = 0.f;
  float accq = 0.f, accd = 0.f;
  if (r < NDOF) {
    q0  = g_state[b*14 + r];
    dq0 = g_state[b*14 + 7 + r];
    float tau = g_action[b*7 + r] * ACTION_RANGE;
    qs = q0; dqs = dq0;
    tauL[r*EP + e] = tau;
  }
  WSYNC();

#pragma unroll 1
  for (int st = 0; st < 4; st++) {
    float bias_reg[NDOF];   // valid on lane r==7

    // ---- (A) adjoint of joint r, lanes r<7: T = exp(-q A) * M^-1 ----
    if (r < NDOF) {
      float Ai[6];
#pragma unroll
      for (int k = 0; k < 6; k++) Ai[k] = sA[r][k];
      float Re[9], pe[3];
      exp_se3(Ai, -qs, Re, pe);
      float IRl[9];
#pragma unroll
      for (int k = 0; k < 9; k++) IRl[k] = sIR[r][k];
      float Tr9[9];
      mat3_mul(Tr9, Re, IRl);
      float Ipl[3] = {sIp[r][0], sIp[r][1], sIp[r][2]};
      float Tp[3];
      mat3_vec(Tp, Re, Ipl);
      Tp[0] += pe[0]; Tp[1] += pe[1]; Tp[2] += pe[2];
#pragma unroll
      for (int k = 0; k < 9; k++) sRB[(r*12 + k)*EP + e] = Tr9[k];
#pragma unroll
      for (int k = 0; k < 3; k++) sRB[(r*12 + 9 + k)*EP + e] = Tp[k];
    }
    WSYNC();
    SCHED_FENCE();

    // ---- (BC) fused forward+backward sweep, ALL 8 lanes ----
    {
      float Phw[NDOF][3], Phv[NDOF][3];
      float Pw[3] = {0.f,0.f,0.f}, Pv[3] = {0.f,0.f,0.f};
      float Qw[3] = {0.f,0.f,0.f}, Qv[3] = {0.f,0.f,0.f};
      if (r == 7) { Qv[0] = -sg[0]; Qv[1] = -sg[1]; Qv[2] = -sg[2]; }
#pragma unroll
      for (int i = 0; i < NDOF; i++) {
        float Rm[9], Tpl[3];
#pragma unroll
        for (int k = 0; k < 9; k++) Rm[k] = sRB[(i*12 + k)*EP + e];
#pragma unroll
        for (int k = 0; k < 3; k++) Tpl[k] = sRB[(i*12 + 9 + k)*EP + e];
        float dqi = __shfl(dqs, base + i, 64);
        float Aw[3] = {sA[i][0], sA[i][1], sA[i][2]};
        float Av[3] = {sA[i][3], sA[i][4], sA[i][5]};
        // P: Pw' = R Pw (+cA*Aw); Pv' = Tp x (R Pw) + R Pv (+cA*Av)
        float Tw[3], t2[3], Tv[3];
        mat3_vec(Tw, Rm, Pw);
        mat3_vec(t2, Rm, Pv);
        cross3(Tv, Tpl, Tw);
        float cA = (r == i) ? 1.f : ((r == 7) ? dqi : 0.f);
#pragma unroll
        for (int k = 0; k < 3; k++) {
          Pw[k] = Tw[k] + cA*Aw[k];
          Pv[k] = Tv[k] + t2[k] + cA*Av[k];
        }
        // Q = AdT*Q + dq_i * ad(P)A_i   (meaningful on lane 7 only)
        float Uw[3], u2[3], Uv[3];
        mat3_vec(Uw, Rm, Qw);
        mat3_vec(u2, Rm, Qv);
        cross3(Uv, Tpl, Uw);
        float c1[3], c2[3], c3[3];
        cross3(c1, Pw, Aw);
        cross3(c2, Pv, Aw);
        cross3(c3, Pw, Av);
        float c8 = (r == 7) ? dqi : 0.f;
#pragma unroll
        for (int k = 0; k < 3; k++) {
          Qw[k] = Uw[k] + c8*c1[k];
          Qv[k] = Uv[k] + u2[k] + c8*(c2[k]+c3[k]);
        }
        if (r == 7) {
#pragma unroll
          for (int k = 0; k < 3; k++) {
            sQh[(i*6 +     k)*EP + e] = Qw[k];
            sQh[(i*6 + 3 + k)*EP + e] = Qv[k];
          }
        }
#pragma unroll
        for (int k = 0; k < 3; k++) { Phw[i][k] = Pw[k]; Phv[i][k] = Pv[k]; }
        SCHED_FENCE();
      }
      // backward: F' = AdT^T F via R^T(Fw + Fv x Tp); R/Tp re-read from LDS
      float Fw[3] = {0.f, 0.f, 0.f}, Fv[3] = {0.f, 0.f, 0.f};
#pragma unroll
      for (int i = NDOF-1; i >= 0; i--) {
        if (i < NDOF-1) {
          const int jn = i + 1;
          float Rm[9], Tpl[3];
#pragma unroll
          for (int k = 0; k < 9; k++) Rm[k] = sRB[(jn*12 + k)*EP + e];
#pragma unroll
          for (int k = 0; k < 3; k++) Tpl[k] = sRB[(jn*12 + 9 + k)*EP + e];
          float cFT[3];
          cross3(cFT, Fv, Tpl);
          float s0[3] = {Fw[0]+cFT[0], Fw[1]+cFT[1], Fw[2]+cFT[2]};
          float nw[3], nv[3];
          mat3T_vec(nw, Rm, s0);
          mat3T_vec(nv, Rm, Fv);
          Fw[0] = nw[0]; Fw[1] = nw[1]; Fw[2] = nw[2];
          Fv[0] = nv[0]; Fv[1] = nv[1]; Fv[2] = nv[2];
        }
        float gx = sG[i][0], gy = sG[i][1], gz = sG[i][2], m_ = sG[i][3];
        float aw[3] = {gx*Phw[i][0], gy*Phw[i][1], gz*Phw[i][2]};
        float av[3] = {m_*Phv[i][0], m_*Phv[i][1], m_*Phv[i][2]};
        float Dw[3], Dv[3];
#pragma unroll
        for (int k = 0; k < 3; k++) {
          Dw[k] = sQh[(i*6 +     k)*EP + e];
          Dv[k] = sQh[(i*6 + 3 + k)*EP + e];
        }
        float GDw[3] = {gx*Dw[0], gy*Dw[1], gz*Dw[2]};
        float GDv[3] = {m_*Dv[0], m_*Dv[1], m_*Dv[2]};
        float x1[3], x2[3], x3[3];
        cross3(x1, Phw[i], aw);   // Vw x GVw  (lane-7 semantics)
        cross3(x2, Phv[i], av);   // Vv x GVv
        cross3(x3, Phw[i], av);   // Vw x GVv
        const bool l7 = (r == 7);
#pragma unroll
        for (int k = 0; k < 3; k++) {
          Fw[k] += l7 ? (GDw[k] + x1[k] + x2[k]) : aw[k];
          Fv[k] += l7 ? (GDv[k] + x3[k])         : av[k];
        }
        float val = Fw[0]*sA[i][0] + Fw[1]*sA[i][1] + Fw[2]*sA[i][2]
                  + Fv[0]*sA[i][3] + Fv[1]*sA[i][4] + Fv[2]*sA[i][5];
        if (r < NDOF && i >= r) MllL[(i*(i+1)/2 + r)*EP + e] = val;
        if (r == 7) bias_reg[i] = val;
        SCHED_FENCE();
      }
    }
    WSYNC();

    // ---- (D) LDL^T solve, lane r==7 (no sqrt in the serial chain) ----
    if (r == 7) {
      float Lm[28], invd[NDOF], dg[NDOF];
#pragma unroll
      for (int idx = 0; idx < 28; idx++) Lm[idx] = MllL[idx*EP + e];
      float y[NDOF];
#pragma unroll
      for (int i = 0; i < NDOF; i++) y[i] = tauL[i*EP + e] - bias_reg[i];
      // factorize: M = L D L^T, L unit-lower (stored in Lm off-diag),
      // dg = D, invd = 1/D. t_j = L_kj * d_j amortizes the d-weighting.
#pragma unroll
      for (int k = 0; k < NDOF; k++) {
        float t[NDOF];
#pragma unroll
        for (int j = 0; j < k; j++) t[j] = Lm[k*(k+1)/2 + j] * dg[j];
        float d = Lm[k*(k+1)/2 + k];
#pragma unroll
        for (int j = 0; j < k; j++) d -= Lm[k*(k+1)/2 + j] * t[j];
        dg[k] = d;
        float inv = 1.0f / d;
        invd[k] = inv;
#pragma unroll
        for (int i = k+1; i < NDOF; i++) {
          float s = Lm[i*(i+1)/2 + k];
#pragma unroll
          for (int j = 0; j < k; j++) s -= Lm[i*(i+1)/2 + j] * t[j];
          Lm[i*(i+1)/2 + k] = s * inv;
        }
      }
      // forward: L z = y (unit diagonal)
#pragma unroll
      for (int i = 0; i < NDOF; i++) {
        float s = y[i];
#pragma unroll
        for (int j = 0; j < i; j++) s -= Lm[i*(i+1)/2 + j] * y[j];
        y[i] = s;
      }
      // scale: w = z / d
#pragma unroll
      for (int i = 0; i < NDOF; i++) y[i] *= invd[i];
      // backward: L^T x = w (unit diagonal)
      float qac[NDOF];
#pragma unroll
      for (int i = NDOF-1; i >= 0; i--) {
        float s = y[i];
#pragma unroll
        for (int m2 = i+1; m2 < NDOF; m2++) s -= Lm[m2*(m2+1)/2 + i] * qac[m2];
        qac[i] = s;
      }
#pragma unroll
      for (int i = 0; i < NDOF; i++) qaccL[i*EP + e] = qac[i];
    }
    WSYNC();

    // ---- (E) RK4 stage update, lanes r<7 ----
    if (r < NDOF) {
      float a = qaccL[r*EP + e];
      float w = (st == 0 || st == 3) ? 1.0f : 2.0f;
      accq += w * dqs;
      accd += w * a;
      if (st < 3) {
        float c = (st == 2) ? HSTEP : 0.5f*HSTEP;
        qs  = q0  + c * dqs;
        dqs = dq0 + c * a;
      }
    }
  }

  const float h6 = HSTEP / 6.0f;
  float qf = 0.f;
  if (r < NDOF) {
    qf = wrap_pi(q0 + h6*accq);
    float v  = dq0 + h6*accd;
    float dqf = fminf(fmaxf(v, -MAX_VEL), MAX_VEL);
    g_out_state[b*14 + r]     = qf;
    g_out_state[b*14 + 7 + r] = dqf;
  }

  // ---- FK: per-lane leaf + 3-step shuffle tree over the 8-lane group ----
  // lane r<7: T_r = M_r * exp(A_r, qf_r); lane 7: T_7 = M_7.
  // Leftward product: lane 0 ends with (M_0 E_0)...(M_6 E_6) M_7; its p is EE.
  float SR[9], Sp[3];
  {
    float MR[9];
#pragma unroll
    for (int k = 0; k < 9; k++) MR[k] = sMR[r][k];
    float Mpl[3] = {sMp[r][0], sMp[r][1], sMp[r][2]};
    if (r < NDOF) {
      float Ai[6];
#pragma unroll
      for (int k = 0; k < 6; k++) Ai[k] = sA[r][k];
      float Re[9], pe[3];
      exp_se3(Ai, qf, Re, pe);
      mat3_mul(SR, MR, Re);
      float t[3];
      mat3_vec(t, MR, pe);
      Sp[0] = t[0] + Mpl[0]; Sp[1] = t[1] + Mpl[1]; Sp[2] = t[2] + Mpl[2];
    } else {
#pragma unroll
      for (int k = 0; k < 9; k++) SR[k] = MR[k];
      Sp[0] = Mpl[0]; Sp[1] = Mpl[1]; Sp[2] = Mpl[2];
    }
  }
#pragma unroll
  for (int off = 1; off < 8; off <<= 1) {
    const int partner = base + ((r + off) & 7);
    float PRm[9], Pp[3];
#pragma unroll
    for (int k = 0; k < 9; k++) PRm[k] = __shfl(SR[k], partner, 64);
#pragma unroll
    for (int k = 0; k < 3; k++) Pp[k] = __shfl(Sp[k], partner, 64);
    float NR[9], Np[3];
    mat3_mul(NR, SR, PRm);
    mat3_vec(Np, SR, Pp);
    Np[0] += Sp[0]; Np[1] += Sp[1]; Np[2] += Sp[2];
#pragma unroll
    for (int k = 0; k < 9; k++) SR[k] = NR[k];
    Sp[0] = Np[0]; Sp[1] = Np[1]; Sp[2] = Np[2];
  }
  if (r == 0) {
    g_out_ee[b*2 + 0] = Sp[0];
    g_out_ee[b*2 + 1] = Sp[1];
  }
}

extern "C" void kernel_launch(void* const* d_in, const int* in_sizes, int n_in,
                              void* d_out, int out_size, void* d_ws, size_t ws_size,
                              hipStream_t stream) {
  const float* state  = (const float*)d_in[0];  // (16384,14)
  const float* action = (const float*)d_in[1];  // (16384,7)
  const float* M      = (const float*)d_in[2];  // (8,4,4)
  const float* A      = (const float*)d_in[3];  // (7,6)
  const float* G      = (const float*)d_in[4];  // (7,4)
  const float* grav   = (const float*)d_in[5];  // (3,)
  float* out_state = (float*)d_out;                       // (16384,14)
  float* out_ee    = (float*)d_out + (size_t)BATCH * 14;  // (16384,2)

  arm_rk4_kernel<<<BATCH / EPB, BLOCK, 0, stream>>>(
      state, action, M, A, G, grav, out_state, out_ee);
}